// Round 2
// baseline (90.018 us; speedup 1.0000x reference)
//
#include <hip/hip_runtime.h>

#define NUM_EXPERTS 8
#define TOPK 2
#define H 2048
#define H4 512            // H / 4 (float4 columns)
#define NTOK 16384        // 4 * 4096 tokens
#define TOK_PER_WAVE 2
#define WAVES_PER_BLOCK 4
#define TOK_PER_BLOCK (TOK_PER_WAVE * WAVES_PER_BLOCK)   // 8
#define AUX_COEF 0.01f

// One wave computes 2 tokens' logits; 2048 blocks -> 8 blocks/CU, 32 waves/CU.
__global__ __launch_bounds__(256, 8)
void router_main(const float* __restrict__ hs, const float* __restrict__ gw,
                 float* __restrict__ out, float* __restrict__ ws)
{
    __shared__ float s_psum[NUM_EXPERTS];
    __shared__ float s_cnt[NUM_EXPERTS];
    const int tid = threadIdx.x;
    if (tid < NUM_EXPERTS) { s_psum[tid] = 0.f; s_cnt[tid] = 0.f; }
    __syncthreads();

    const int wave = tid >> 6;
    const int lane = tid & 63;
    const int tok0 = blockIdx.x * TOK_PER_BLOCK + wave * TOK_PER_WAVE;

    const float4* __restrict__ hs4 = (const float4*)hs;
    const float4* __restrict__ gw4 = (const float4*)gw;

    float acc0[NUM_EXPERTS], acc1[NUM_EXPERTS];
    #pragma unroll
    for (int e = 0; e < NUM_EXPERTS; ++e) { acc0[e] = 0.f; acc1[e] = 0.f; }

    // 512 float4 cols per token; lane covers col = it*64 + lane
    #pragma unroll 2
    for (int it = 0; it < 8; ++it) {
        const int col = it * 64 + lane;
        const float4 h0 = hs4[(size_t)tok0 * H4 + col];
        const float4 h1 = hs4[(size_t)(tok0 + 1) * H4 + col];
        #pragma unroll
        for (int e = 0; e < NUM_EXPERTS; ++e) {
            const float4 g = gw4[e * H4 + col];
            acc0[e] += h0.x * g.x + h0.y * g.y + h0.z * g.z + h0.w * g.w;
            acc1[e] += h1.x * g.x + h1.y * g.y + h1.z * g.z + h1.w * g.w;
        }
    }

    // full-wave butterfly: every lane ends with complete dots for both tokens
    #pragma unroll
    for (int e = 0; e < NUM_EXPERTS; ++e) {
        float v0 = acc0[e], v1 = acc1[e];
        #pragma unroll
        for (int s = 32; s > 0; s >>= 1) {
            v0 += __shfl_xor(v0, s, 64);
            v1 += __shfl_xor(v1, s, 64);
        }
        acc0[e] = v0; acc1[e] = v1;
    }

    // lane parity picks its token; static indexing only (no runtime array idx)
    const bool odd = (lane & 1);
    float lg[NUM_EXPERTS];
    #pragma unroll
    for (int e = 0; e < NUM_EXPERTS; ++e) lg[e] = odd ? acc1[e] : acc0[e];

    float m = lg[0];
    #pragma unroll
    for (int e = 1; e < NUM_EXPERTS; ++e) m = fmaxf(m, lg[e]);
    float p[NUM_EXPERTS];
    float s = 0.f;
    #pragma unroll
    for (int e = 0; e < NUM_EXPERTS; ++e) { p[e] = __expf(lg[e] - m); s += p[e]; }
    const float inv = 1.f / s;

    // top-2 on probs; strict '>' keeps lowest index on ties (lax.top_k order)
    float v0 = -1.f; int i0 = 0;
    #pragma unroll
    for (int e = 0; e < NUM_EXPERTS; ++e) { if (p[e] > v0) { v0 = p[e]; i0 = e; } }
    float v1 = -1.f; int i1 = 0;
    #pragma unroll
    for (int e = 0; e < NUM_EXPERTS; ++e) { if (e != i0 && p[e] > v1) { v1 = p[e]; i1 = e; } }

    if (lane < 2) {
        const int tok = tok0 + lane;
        const float wsum = v0 + v1;
        out[tok * 2 + 0] = v0 / wsum;
        out[tok * 2 + 1] = v1 / wsum;
        out[2 * NTOK + tok * 2 + 0] = (float)i0;
        out[2 * NTOK + tok * 2 + 1] = (float)i1;
        #pragma unroll
        for (int e = 0; e < NUM_EXPERTS; ++e) atomicAdd(&s_psum[e], p[e] * inv);
        atomicAdd(&s_cnt[i0], 1.f);
        atomicAdd(&s_cnt[i1], 1.f);
    }

    __syncthreads();
    if (tid < NUM_EXPERTS) {
        atomicAdd(&ws[tid], s_psum[tid]);
        atomicAdd(&ws[NUM_EXPERTS + tid], s_cnt[tid]);
    }
}

// aux = E * sum(expert_frac * router_frac) * coef
__global__ void router_aux(const float* __restrict__ ws, float* __restrict__ out)
{
    if (threadIdx.x == 0 && blockIdx.x == 0) {
        float s = 0.f;
        #pragma unroll
        for (int e = 0; e < NUM_EXPERTS; ++e) {
            const float ef = ws[NUM_EXPERTS + e] / (float)(NTOK * TOPK);
            const float rf = ws[e] / (float)NTOK;
            s += ef * rf;
        }
        out[4 * NTOK] = (float)NUM_EXPERTS * s * AUX_COEF;
    }
}

extern "C" void kernel_launch(void* const* d_in, const int* in_sizes, int n_in,
                              void* d_out, int out_size, void* d_ws, size_t ws_size,
                              hipStream_t stream)
{
    const float* hs = (const float*)d_in[0];   // [4,4096,2048] f32
    const float* gw = (const float*)d_in[1];   // [8,2048] f32
    float* out = (float*)d_out;                // 32768 rw | 32768 idx | 1 aux
    float* ws  = (float*)d_ws;                 // 16 floats of accumulators

    hipMemsetAsync(d_ws, 0, 2 * NUM_EXPERTS * sizeof(float), stream);
    hipLaunchKernelGGL(router_main, dim3(NTOK / TOK_PER_BLOCK), dim3(256), 0, stream,
                       hs, gw, out, ws);
    hipLaunchKernelGGL(router_aux, dim3(1), dim3(64), 0, stream, ws, out);
}

// Round 3
// 82.074 us; speedup vs baseline: 1.0968x; 1.0968x over previous
//
#include <hip/hip_runtime.h>

#define NUM_EXPERTS 8
#define TOPK 2
#define H4 512            // 2048 / 4 (float4 columns)
#define NTOK 16384        // 4 * 4096 tokens
#define TPW 4             // tokens per wave
#define WPB 4             // waves per block
#define TPB (TPW * WPB)   // 16 tokens per block
#define AUX_COEF 0.01f

// One wave computes 4 tokens' logits with explicit h-prefetch pipelining.
// grid = 1024 blocks (4/CU), 16 waves/CU, ~4 KB/wave HBM loads in flight.
__global__ __launch_bounds__(256, 4)
void router_main(const float* __restrict__ hs, const float* __restrict__ gw,
                 float* __restrict__ out, float* __restrict__ ws)
{
    __shared__ float s_psum[NUM_EXPERTS];
    __shared__ float s_cnt[NUM_EXPERTS];
    const int tid = threadIdx.x;
    if (tid < NUM_EXPERTS) { s_psum[tid] = 0.f; s_cnt[tid] = 0.f; }
    __syncthreads();

    const int wave = tid >> 6;
    const int lane = tid & 63;
    const int tok0 = blockIdx.x * TPB + wave * TPW;

    const float4* __restrict__ hs4 = (const float4*)hs;
    const float4* __restrict__ gw4 = (const float4*)gw;
    const size_t rowbase = (size_t)tok0 * H4;

    float acc[TPW][NUM_EXPERTS];
    #pragma unroll
    for (int t = 0; t < TPW; ++t)
        #pragma unroll
        for (int e = 0; e < NUM_EXPERTS; ++e) acc[t][e] = 0.f;

    // prologue: load h for it=0
    float4 h[TPW], hn[TPW];
    #pragma unroll
    for (int t = 0; t < TPW; ++t) h[t] = hs4[rowbase + (size_t)t * H4 + lane];

    #pragma unroll 2
    for (int it = 0; it < 8; ++it) {
        const int col = it * 64 + lane;
        // gate loads for current iter (L1/L2 stream)
        float4 g[NUM_EXPERTS];
        #pragma unroll
        for (int e = 0; e < NUM_EXPERTS; ++e) g[e] = gw4[e * H4 + col];
        // prefetch next iter's hidden (HBM stream) — stays in flight over FMAs
        if (it < 7) {
            #pragma unroll
            for (int t = 0; t < TPW; ++t)
                hn[t] = hs4[rowbase + (size_t)t * H4 + col + 64];
        }
        #pragma unroll
        for (int e = 0; e < NUM_EXPERTS; ++e)
            #pragma unroll
            for (int t = 0; t < TPW; ++t)
                acc[t][e] += h[t].x * g[e].x + h[t].y * g[e].y
                           + h[t].z * g[e].z + h[t].w * g[e].w;
        #pragma unroll
        for (int t = 0; t < TPW; ++t) h[t] = hn[t];
    }

    // full-wave butterfly: every lane ends with complete dots for all 4 tokens
    #pragma unroll
    for (int t = 0; t < TPW; ++t) {
        #pragma unroll
        for (int e = 0; e < NUM_EXPERTS; ++e) {
            float v = acc[t][e];
            #pragma unroll
            for (int s = 32; s > 0; s >>= 1) v += __shfl_xor(v, s, 64);
            acc[t][e] = v;
        }
    }

    // lane (mod 4) picks its token — static indexing only
    const int ls = lane & 3;
    float lg[NUM_EXPERTS];
    #pragma unroll
    for (int e = 0; e < NUM_EXPERTS; ++e)
        lg[e] = (ls == 0) ? acc[0][e] : (ls == 1) ? acc[1][e]
              : (ls == 2) ? acc[2][e] : acc[3][e];

    float m = lg[0];
    #pragma unroll
    for (int e = 1; e < NUM_EXPERTS; ++e) m = fmaxf(m, lg[e]);
    float p[NUM_EXPERTS];
    float s = 0.f;
    #pragma unroll
    for (int e = 0; e < NUM_EXPERTS; ++e) { p[e] = __expf(lg[e] - m); s += p[e]; }
    const float inv = 1.f / s;

    // top-2 on probs; strict '>' keeps lowest index on ties (lax.top_k order)
    float v0 = -1.f; int i0 = 0;
    #pragma unroll
    for (int e = 0; e < NUM_EXPERTS; ++e) { if (p[e] > v0) { v0 = p[e]; i0 = e; } }
    float v1 = -1.f; int i1 = 0;
    #pragma unroll
    for (int e = 0; e < NUM_EXPERTS; ++e) { if (e != i0 && p[e] > v1) { v1 = p[e]; i1 = e; } }

    if (lane < TPW) {
        const int tok = tok0 + lane;
        const float wsum = v0 + v1;
        out[tok * 2 + 0] = v0 / wsum;
        out[tok * 2 + 1] = v1 / wsum;
        out[2 * NTOK + tok * 2 + 0] = (float)i0;
        out[2 * NTOK + tok * 2 + 1] = (float)i1;
        #pragma unroll
        for (int e = 0; e < NUM_EXPERTS; ++e) atomicAdd(&s_psum[e], p[e] * inv);
        atomicAdd(&s_cnt[i0], 1.f);
        atomicAdd(&s_cnt[i1], 1.f);
    }

    __syncthreads();
    if (tid < NUM_EXPERTS) {
        atomicAdd(&ws[tid], s_psum[tid]);
        atomicAdd(&ws[NUM_EXPERTS + tid], s_cnt[tid]);
    }
}

// aux = E * sum(expert_frac * router_frac) * coef
__global__ void router_aux(const float* __restrict__ ws, float* __restrict__ out)
{
    if (threadIdx.x == 0 && blockIdx.x == 0) {
        float s = 0.f;
        #pragma unroll
        for (int e = 0; e < NUM_EXPERTS; ++e) {
            const float ef = ws[NUM_EXPERTS + e] / (float)(NTOK * TOPK);
            const float rf = ws[e] / (float)NTOK;
            s += ef * rf;
        }
        out[4 * NTOK] = (float)NUM_EXPERTS * s * AUX_COEF;
    }
}

extern "C" void kernel_launch(void* const* d_in, const int* in_sizes, int n_in,
                              void* d_out, int out_size, void* d_ws, size_t ws_size,
                              hipStream_t stream)
{
    const float* hs = (const float*)d_in[0];   // [4,4096,2048] f32
    const float* gw = (const float*)d_in[1];   // [8,2048] f32
    float* out = (float*)d_out;                // 32768 rw | 32768 idx | 1 aux
    float* ws  = (float*)d_ws;                 // 16 floats of accumulators

    hipMemsetAsync(d_ws, 0, 2 * NUM_EXPERTS * sizeof(float), stream);
    hipLaunchKernelGGL(router_main, dim3(NTOK / TPB), dim3(256), 0, stream,
                       hs, gw, out, ws);
    hipLaunchKernelGGL(router_aux, dim3(1), dim3(64), 0, stream, ws, out);
}

// Round 5
// 60.932 us; speedup vs baseline: 1.4773x; 1.3470x over previous
//
#include <hip/hip_runtime.h>

#define NE 8              // experts
#define H4 512            // float4 per token row (2048 floats)
#define NTOK 16384        // 4 * 4096 tokens
#define TPW 4             // tokens per wave
#define WPB 4             // waves per block
#define TPB (TPW * WPB)   // 16 tokens per block
#define KC 8              // K-steps
#define C4 64             // float4 per chunk (256 floats = 1 KB)
#define AUX_COEF 0.01f

typedef const __attribute__((address_space(1))) void* gas_ptr;
typedef __attribute__((address_space(3))) void* lds_ptr;

// Async-staged router: global_load_lds keeps the HBM stream off the VGPRs,
// counted vmcnt(12) keeps 12 loads/wave in flight (no __syncthreads in loop).
// Last K-step is PEELED with a vmcnt(0) drain: no dummy ops, so compiler CSE
// cannot change the per-segment issue count the vmcnt arithmetic relies on.
__global__ __launch_bounds__(256)
void router_main(const float* __restrict__ hs, const float* __restrict__ gw,
                 float* __restrict__ out, float* __restrict__ ws)
{
    __shared__ float4 buf[2][TPB][C4];       // 2 x 16 x 1 KB = 32 KB
    __shared__ float s_psum[NE], s_cnt[NE];
    const int tid = threadIdx.x;
    if (tid < NE) { s_psum[tid] = 0.f; s_cnt[tid] = 0.f; }
    __syncthreads();

    const int wave = tid >> 6, lane = tid & 63;
    const int tok0 = blockIdx.x * TPB + wave * TPW;
    const float4* __restrict__ hs4 = (const float4*)hs;
    const float4* __restrict__ gw4 = (const float4*)gw;

    float acc[TPW][NE];
    #pragma unroll
    for (int r = 0; r < TPW; ++r)
        #pragma unroll
        for (int e = 0; e < NE; ++e) acc[r][e] = 0.f;

    float4 g[NE], gn[NE];
    #pragma unroll
    for (int e = 0; e < NE; ++e) g[e] = gw4[e * H4 + lane];      // g(0): 8 ops
    #pragma unroll
    for (int r = 0; r < TPW; ++r)                                 // stage(0): 4 ops
        __builtin_amdgcn_global_load_lds(
            (gas_ptr)(hs4 + (size_t)(tok0 + r) * H4 + lane),
            (lds_ptr)&buf[0][wave * TPW + r][0], 16, 0, 0);

    // main loop kc = 0..6: each segment issues exactly 12 VMEM ops, then
    // vmcnt(12) retires exactly the previous segment (incl. its stage).
    #pragma unroll
    for (int kc = 0; kc < KC - 1; ++kc) {
        const int kn = kc + 1;
        #pragma unroll
        for (int r = 0; r < TPW; ++r)
            __builtin_amdgcn_global_load_lds(
                (gas_ptr)(hs4 + (size_t)(tok0 + r) * H4 + kn * C4 + lane),
                (lds_ptr)&buf[kn & 1][wave * TPW + r][0], 16, 0, 0);
        #pragma unroll
        for (int e = 0; e < NE; ++e) gn[e] = gw4[e * H4 + kn * C4 + lane];
        asm volatile("s_waitcnt vmcnt(12)" ::: "memory");
        #pragma unroll
        for (int r = 0; r < TPW; ++r) {
            const float4 h = buf[kc & 1][wave * TPW + r][lane];
            #pragma unroll
            for (int e = 0; e < NE; ++e)
                acc[r][e] += h.x * g[e].x + h.y * g[e].y
                           + h.z * g[e].z + h.w * g[e].w;
        }
        #pragma unroll
        for (int e = 0; e < NE; ++e) g[e] = gn[e];
    }

    // peeled last K-step: nothing left to overlap — full drain, then compute
    asm volatile("s_waitcnt vmcnt(0)" ::: "memory");
    #pragma unroll
    for (int r = 0; r < TPW; ++r) {
        const float4 h = buf[(KC - 1) & 1][wave * TPW + r][lane];
        #pragma unroll
        for (int e = 0; e < NE; ++e)
            acc[r][e] += h.x * g[e].x + h.y * g[e].y
                       + h.z * g[e].z + h.w * g[e].w;
    }

    // full-wave butterfly: every lane ends with complete dots for all 4 tokens
    #pragma unroll
    for (int r = 0; r < TPW; ++r) {
        #pragma unroll
        for (int e = 0; e < NE; ++e) {
            float v = acc[r][e];
            #pragma unroll
            for (int s = 32; s > 0; s >>= 1) v += __shfl_xor(v, s, 64);
            acc[r][e] = v;
        }
    }

    // lane (mod 4) picks its token — static indexing only
    const int ls = lane & 3;
    float lg[NE];
    #pragma unroll
    for (int e = 0; e < NE; ++e)
        lg[e] = (ls == 0) ? acc[0][e] : (ls == 1) ? acc[1][e]
              : (ls == 2) ? acc[2][e] : acc[3][e];

    float m = lg[0];
    #pragma unroll
    for (int e = 1; e < NE; ++e) m = fmaxf(m, lg[e]);
    float p[NE];
    float s = 0.f;
    #pragma unroll
    for (int e = 0; e < NE; ++e) { p[e] = __expf(lg[e] - m); s += p[e]; }
    const float inv = 1.f / s;

    // top-2 on probs; strict '>' keeps lowest index on ties (lax.top_k order)
    float v0 = -1.f; int i0 = 0;
    #pragma unroll
    for (int e = 0; e < NE; ++e) { if (p[e] > v0) { v0 = p[e]; i0 = e; } }
    float v1 = -1.f; int i1 = 0;
    #pragma unroll
    for (int e = 0; e < NE; ++e) { if (e != i0 && p[e] > v1) { v1 = p[e]; i1 = e; } }

    if (lane < TPW) {
        const int tok = tok0 + ls;
        const float wsum = v0 + v1;
        out[tok * 2 + 0] = v0 / wsum;
        out[tok * 2 + 1] = v1 / wsum;
        out[2 * NTOK + tok * 2 + 0] = (float)i0;
        out[2 * NTOK + tok * 2 + 1] = (float)i1;
        #pragma unroll
        for (int e = 0; e < NE; ++e) atomicAdd(&s_psum[e], p[e] * inv);
        atomicAdd(&s_cnt[i0], 1.f);
        atomicAdd(&s_cnt[i1], 1.f);
    }

    __syncthreads();
    if (tid < NE) {
        atomicAdd(&ws[tid], s_psum[tid]);
        atomicAdd(&ws[NE + tid], s_cnt[tid]);
    }
}

// aux = E * sum(expert_frac * router_frac) * coef
__global__ void router_aux(const float* __restrict__ ws, float* __restrict__ out)
{
    if (threadIdx.x == 0 && blockIdx.x == 0) {
        float s = 0.f;
        #pragma unroll
        for (int e = 0; e < NE; ++e) {
            const float ef = ws[NE + e] / (float)(NTOK * 2);
            const float rf = ws[e] / (float)NTOK;
            s += ef * rf;
        }
        out[4 * NTOK] = (float)NE * s * AUX_COEF;
    }
}

extern "C" void kernel_launch(void* const* d_in, const int* in_sizes, int n_in,
                              void* d_out, int out_size, void* d_ws, size_t ws_size,
                              hipStream_t stream)
{
    const float* hs = (const float*)d_in[0];   // [4,4096,2048] f32
    const float* gw = (const float*)d_in[1];   // [8,2048] f32
    float* out = (float*)d_out;                // 32768 rw | 32768 idx | 1 aux
    float* ws  = (float*)d_ws;                 // 16 floats of accumulators

    hipMemsetAsync(d_ws, 0, 2 * NE * sizeof(float), stream);
    hipLaunchKernelGGL(router_main, dim3(NTOK / TPB), dim3(256), 0, stream,
                       hs, gw, out, ws);
    hipLaunchKernelGGL(router_aux, dim3(1), dim3(64), 0, stream, ws, out);
}